// Round 4
// baseline (1467.898 us; speedup 1.0000x reference)
//
#include <hip/hip_runtime.h>
#include <hip/hip_bf16.h>

// LIF layer: lif_input[T,NOUT] = x[T,NIN] @ W[NOUT,NIN]^T (fp32), then sequential scan.
// fp32 GEMM on matrix pipe via fp16 2-way SCALED split, 3 MFMA products:
//   a = a0 + a1*2^-12 (a1 pre-scaled by 2^12: dodges fp16 subnormal flush)
//   C = acc0(A0B0) + 2^-12 * acc1(A0B1 + A1B0); error ~2^-24|ab| (fp32-noise level).
// Round-4 changes:
//  - wave tile 64x32 (acc 64 regs), __launch_bounds__(256,2) -> 2 waves/SIMD,
//    2 resident blocks/CU (round 3: 276 regs -> 1 wave/SIMD, Occupancy 12%).
//  - bank-conflict XOR swizzle: split kernel stores 16B k-group g of row r at
//    position g^(r&3); GEMM reads LDS at quad^(r&3). Breaks the 64B-row-stride
//    8-way conflict (3.35e7 conflict cycles in round 3).
//  - scan: explicit 16-deep register prefetch pipeline.

#define T_STEPS 2000
#define NIN_K   8192
#define NOUT_N  4096
#define MPAD    2048

typedef __attribute__((ext_vector_type(8))) _Float16 half8;  // 8 fp16 = 4 VGPRs
typedef __attribute__((ext_vector_type(4))) float f32x4;

#define GLL16(g, l)                                                              \
    __builtin_amdgcn_global_load_lds(                                            \
        (const __attribute__((address_space(1))) void*)(g),                      \
        (__attribute__((address_space(3))) void*)(l), 16, 0, 0)

// ---------------- decompose: fp32 -> (hi, lo*2^12) fp16, bank-swizzled ----------------
// Each thread: 8 consecutive floats -> one 16B hi group + one 16B lo group,
// stored at swizzled k-group position g' = (g & ~3) | ((g ^ row) & 3).
__global__ __launch_bounds__(256) void split_f32_swz(const float* __restrict__ src,
                                                     _Float16* __restrict__ hi,
                                                     _Float16* __restrict__ lo,
                                                     size_t n_valid) {
    const size_t i8 = (size_t)(blockIdx.x * 256u + threadIdx.x) * 8;
    const size_t row = i8 >> 13;          // / NIN_K
    const int    col = (int)(i8 & 8191);  // % NIN_K
    const int    g   = col >> 3;
    const int    gs  = (g & ~3) | ((g ^ (int)row) & 3);
    const size_t ob  = (row << 13) + ((size_t)gs << 3);

    float vv[8];
    if (i8 < n_valid) {
        float4 v0 = *(const float4*)(src + i8);
        float4 v1 = *(const float4*)(src + i8 + 4);
        vv[0] = v0.x; vv[1] = v0.y; vv[2] = v0.z; vv[3] = v0.w;
        vv[4] = v1.x; vv[5] = v1.y; vv[6] = v1.z; vv[7] = v1.w;
    } else {
#pragma unroll
        for (int j = 0; j < 8; ++j) vv[j] = 0.f;
    }
    half8 h8, l8;
#pragma unroll
    for (int j = 0; j < 8; ++j) {
        _Float16 h = (_Float16)vv[j];               // RN
        float r = __fsub_rn(vv[j], (float)h);       // exact
        h8[j] = h;
        l8[j] = (_Float16)(r * 4096.0f);            // exact shift + one RN
    }
    *(half8*)(hi + ob) = h8;
    *(half8*)(lo + ob) = l8;
}

// ---------------- split-fp16 MFMA GEMM ----------------
// Block tile 128x64, BK=32, 4 waves of 64x32 (4x2 frags of 16x16x32).
__global__ __launch_bounds__(256, 2) void gemm_f16x2(const _Float16* __restrict__ A0,
                                                     const _Float16* __restrict__ A1,
                                                     const _Float16* __restrict__ B0,
                                                     const _Float16* __restrict__ B1,
                                                     float* __restrict__ C) {
    __shared__ _Float16 ldsA[2][128 * 32];  // 8 KB each
    __shared__ _Float16 ldsB[2][64 * 32];   // 4 KB each; total 24 KB

    const int tid  = threadIdx.x;
    const int wave = tid >> 6;
    const int lane = tid & 63;
    const int bm = blockIdx.y * 128;
    const int bn = blockIdx.x * 64;
    const int wm = (wave >> 1) * 64;   // 0 or 64
    const int wn = (wave & 1) * 32;    // 0 or 32

    const int srow  = tid >> 2;        // 0..63
    const int skoff = (tid & 3) * 8;   // 0,8,16,24

    f32x4 acc0[4][2], acc1[4][2];
#pragma unroll
    for (int i = 0; i < 4; ++i)
#pragma unroll
        for (int j = 0; j < 2; ++j) {
            acc0[i][j] = (f32x4){0.f, 0.f, 0.f, 0.f};
            acc1[i][j] = (f32x4){0.f, 0.f, 0.f, 0.f};
        }

    const int quad = lane >> 4;        // 0..3
    const int l16  = lane & 15;
    const int xq   = (quad ^ (l16 & 3)) * 8;  // swizzled k-offset (row&3 == l16&3)

    for (int k0 = 0; k0 < NIN_K; k0 += 32) {
        __syncthreads();
#pragma unroll
        for (int c = 0; c < 2; ++c) {  // A: two 64-row chunks
            const size_t ga = (size_t)(bm + c * 64 + srow) * NIN_K + k0 + skoff;
            const int ldst = (c * 64 + wave * 16) * 32;  // wave-uniform
            GLL16(A0 + ga, &ldsA[0][ldst]);
            GLL16(A1 + ga, &ldsA[1][ldst]);
        }
        {                              // B: one 64-row chunk
            const size_t gb = (size_t)(bn + srow) * NIN_K + k0 + skoff;
            const int ldst = (wave * 16) * 32;
            GLL16(B0 + gb, &ldsB[0][ldst]);
            GLL16(B1 + gb, &ldsB[1][ldst]);
        }
        __syncthreads();

        half8 a0[4], a1[4], b0[2], b1[2];
#pragma unroll
        for (int i = 0; i < 4; ++i) {
            const int off = (wm + i * 16 + l16) * 32 + xq;
            a0[i] = *(const half8*)&ldsA[0][off];
            a1[i] = *(const half8*)&ldsA[1][off];
        }
#pragma unroll
        for (int j = 0; j < 2; ++j) {
            const int off = (wn + j * 16 + l16) * 32 + xq;
            b0[j] = *(const half8*)&ldsB[0][off];
            b1[j] = *(const half8*)&ldsB[1][off];
        }
#pragma unroll
        for (int i = 0; i < 4; ++i)
#pragma unroll
            for (int j = 0; j < 2; ++j) {
                acc0[i][j] = __builtin_amdgcn_mfma_f32_16x16x32_f16(a0[i], b0[j], acc0[i][j], 0, 0, 0);
                acc1[i][j] = __builtin_amdgcn_mfma_f32_16x16x32_f16(a0[i], b1[j], acc1[i][j], 0, 0, 0);
                acc1[i][j] = __builtin_amdgcn_mfma_f32_16x16x32_f16(a1[i], b0[j], acc1[i][j], 0, 0, 0);
            }
    }

    // C/D layout: col = lane&15, row = quad*4 + reg (dtype-independent, m89)
    const float s = 1.0f / 4096.0f;
#pragma unroll
    for (int i = 0; i < 4; ++i)
#pragma unroll
        for (int j = 0; j < 2; ++j) {
            const int m = bm + wm + i * 16 + quad * 4;
            const int n = bn + wn + j * 16 + l16;
            float* cp = C + (size_t)m * NOUT_N + n;
#pragma unroll
            for (int r = 0; r < 4; ++r)
                cp[(size_t)r * NOUT_N] = __fmaf_rn(acc1[i][j][r], s, acc0[i][j][r]);
        }
}

// ---------------- fallback fp32 GEMM (round-1 proven; reads RAW x/w) ----------------
#define BM 64
#define BN 64
#define BK 16
#define PAD 4
__global__ __launch_bounds__(256) void gemm_bt(const float* __restrict__ A,
                                               const float* __restrict__ B,
                                               float* __restrict__ C,
                                               int M, int N, int K) {
    __shared__ float As[BK][BM + PAD];
    __shared__ float Bs[BK][BN + PAD];
    const int bm = blockIdx.y * BM, bn = blockIdx.x * BN;
    const int tid = threadIdx.x;
    const int tx = tid & 15, ty = tid >> 4;
    const int lrow = tid >> 2, lk = (tid & 3) * 4;
    float acc[4][4];
#pragma unroll
    for (int i = 0; i < 4; ++i)
#pragma unroll
        for (int j = 0; j < 4; ++j) acc[i][j] = 0.0f;
    for (int k0 = 0; k0 < K; k0 += BK) {
        const int am = bm + lrow;
        float4 av = (am < M) ? *(const float4*)(A + (size_t)am * K + k0 + lk)
                             : make_float4(0.f, 0.f, 0.f, 0.f);
        As[lk + 0][lrow] = av.x; As[lk + 1][lrow] = av.y;
        As[lk + 2][lrow] = av.z; As[lk + 3][lrow] = av.w;
        float4 bv = *(const float4*)(B + (size_t)(bn + lrow) * K + k0 + lk);
        Bs[lk + 0][lrow] = bv.x; Bs[lk + 1][lrow] = bv.y;
        Bs[lk + 2][lrow] = bv.z; Bs[lk + 3][lrow] = bv.w;
        __syncthreads();
#pragma unroll
        for (int k = 0; k < BK; ++k) {
            float a[4], b[4];
#pragma unroll
            for (int i = 0; i < 4; ++i) a[i] = As[k][ty * 4 + i];
#pragma unroll
            for (int j = 0; j < 4; ++j) b[j] = Bs[k][tx * 4 + j];
#pragma unroll
            for (int i = 0; i < 4; ++i)
#pragma unroll
                for (int j = 0; j < 4; ++j) acc[i][j] += a[i] * b[j];
        }
        __syncthreads();
    }
#pragma unroll
    for (int i = 0; i < 4; ++i) {
        const int m = bm + ty * 4 + i;
        if (m < M) {
            float* cp = C + (size_t)m * N + bn + tx * 4;
#pragma unroll
            for (int j = 0; j < 4; ++j) cp[j] = acc[i][j];
        }
    }
}

// ---------------- sequential LIF scan, 16-deep load pipeline ----------------
#define SCAN_D 16
__global__ __launch_bounds__(64) void lif_scan(const float* __restrict__ inp,
                                               const float* __restrict__ v_th_p,
                                               const float* __restrict__ v_rest_p,
                                               const float* __restrict__ v_reset_p,
                                               const float* __restrict__ t_ref_p,
                                               const float* __restrict__ tau_p,
                                               float* __restrict__ out,
                                               int T, int N) {
    const int j = blockIdx.x * 64 + threadIdx.x;
    if (j >= N) return;
    const float vth = v_th_p[j], vrest = v_rest_p[j], vres = v_reset_p[j];
    const float tref = t_ref_p[j];
    const float c = __fmul_rn(0.001f, tau_p[j]);
    float v = vrest, refrac = 0.0f;
    out[j] = 0.0f;

    float pf[SCAN_D];
#pragma unroll
    for (int d = 0; d < SCAN_D; ++d) pf[d] = inp[(size_t)(1 + d) * N + j];

    int base = 1;
    for (; base + SCAN_D <= T; base += SCAN_D) {
#pragma unroll
        for (int d = 0; d < SCAN_D; ++d) {
            const float in = pf[d];
            const int tf = base + d + SCAN_D;
            if (tf < T) pf[d] = inp[(size_t)tf * N + j];
            const float dd = __fmul_rn(c, __fsub_rn(v, vrest));
            v = __fsub_rn(v, dd);
            v = (refrac == 0.0f) ? __fadd_rn(v, in) : v;
            refrac = (refrac > 0.0f) ? (refrac - 0.001f) : 0.0f;
            const bool s = (__fsub_rn(v, vth) >= 0.0f);
            out[(size_t)(base + d) * N + j] = s ? 1.0f : 0.0f;
            refrac = s ? tref : refrac;
            v = s ? vres : v;
        }
    }
#pragma unroll
    for (int d = 0; d < SCAN_D; ++d) {
        const int t = base + d;
        if (t < T) {
            const float in = pf[d];
            const float dd = __fmul_rn(c, __fsub_rn(v, vrest));
            v = __fsub_rn(v, dd);
            v = (refrac == 0.0f) ? __fadd_rn(v, in) : v;
            refrac = (refrac > 0.0f) ? (refrac - 0.001f) : 0.0f;
            const bool s = (__fsub_rn(v, vth) >= 0.0f);
            out[(size_t)t * N + j] = s ? 1.0f : 0.0f;
            refrac = s ? tref : refrac;
            v = s ? vres : v;
        }
    }
}

extern "C" void kernel_launch(void* const* d_in, const int* in_sizes, int n_in,
                              void* d_out, int out_size, void* d_ws, size_t ws_size,
                              hipStream_t stream) {
    const float* x       = (const float*)d_in[0];
    const float* w       = (const float*)d_in[1];
    const float* v_th    = (const float*)d_in[2];
    const float* v_rest  = (const float*)d_in[3];
    const float* v_reset = (const float*)d_in[4];
    const float* t_ref   = (const float*)d_in[5];
    const float* tau     = (const float*)d_in[6];
    float* out = (float*)d_out;

    const size_t LIF_B = (size_t)MPAD * NOUT_N * 4;        //  32 MiB
    const size_t XS_B  = (size_t)MPAD * NIN_K * 2;         //  32 MiB each
    const size_t WS_B  = (size_t)NOUT_N * NIN_K * 2;       //  64 MiB each
    const size_t NEED  = LIF_B + 2 * XS_B + 2 * WS_B;      // 224 MiB

    char* ws = (char*)d_ws;
    float* lif = (float*)ws;

    if (ws_size >= NEED) {
        _Float16* x0 = (_Float16*)(ws + LIF_B);
        _Float16* x1 = (_Float16*)(ws + LIF_B + XS_B);
        _Float16* w0 = (_Float16*)(ws + LIF_B + 2 * XS_B);
        _Float16* w1 = (_Float16*)(ws + LIF_B + 2 * XS_B + WS_B);

        const size_t nx = (size_t)MPAD * NIN_K;
        split_f32_swz<<<nx / 8 / 256, 256, 0, stream>>>(x, x0, x1,
                                                        (size_t)T_STEPS * NIN_K);
        const size_t nw = (size_t)NOUT_N * NIN_K;
        split_f32_swz<<<nw / 8 / 256, 256, 0, stream>>>(w, w0, w1, nw);

        dim3 g(NOUT_N / 64, MPAD / 128);
        gemm_f16x2<<<g, 256, 0, stream>>>(x0, x1, w0, w1, lif);
    } else {
        dim3 g(NOUT_N / BN, (T_STEPS + BM - 1) / BM);
        gemm_bt<<<g, 256, 0, stream>>>(x, w, lif, T_STEPS, NOUT_N, NIN_K);
    }

    lif_scan<<<NOUT_N / 64, 64, 0, stream>>>(lif, v_th, v_rest, v_reset, t_ref, tau,
                                             out, T_STEPS, NOUT_N);
}

// Round 5
// 791.531 us; speedup vs baseline: 1.8545x; 1.8545x over previous
//
#include <hip/hip_runtime.h>
#include <hip/hip_bf16.h>

// LIF layer: lif_input[T,NOUT] = x[T,NIN] @ W[NOUT,NIN]^T (fp32), then sequential scan.
// fp32 GEMM on matrix pipe via fp16 2-way SCALED split, 3 MFMA products:
//   a = a0 + a1*2^-12 (a1 pre-scaled by 2^12: dodges fp16 subnormal flush)
//   C = acc0(A0B0) + 2^-12 * acc1(A0B1 + A1B0); error ~2^-24|ab| (fp32-noise level).
// Round-5 changes:
//  - GEMM back to 128x128 tile / 64x64 wave tile (best FLOP per staging byte),
//    with __launch_bounds__(256,2) to force 2 waves/SIMD (round 3 allocator
//    sprawled to 276 regs at default min-waves=1 -> 12% occupancy).
//    B-frags hoisted, A-frags loaded per-i to shrink live range (~210 regs).
//  - swizzle removed (round 4 measured: zero effect on conflict rate).
//  - scan: 32-deep register pipeline with UNCONDITIONAL clamped-index loads
//    (round 4's conditional pf[] write demoted the array to scratch: VGPR=24).

#define T_STEPS 2000
#define NIN_K   8192
#define NOUT_N  4096
#define MPAD    2048

typedef __attribute__((ext_vector_type(8))) _Float16 half8;  // 8 fp16 = 4 VGPRs
typedef __attribute__((ext_vector_type(4))) float f32x4;

#define GLL16(g, l)                                                              \
    __builtin_amdgcn_global_load_lds(                                            \
        (const __attribute__((address_space(1))) void*)(g),                      \
        (__attribute__((address_space(3))) void*)(l), 16, 0, 0)

// ---------------- decompose: fp32 -> (hi, lo*2^12) fp16 ----------------
// h = RN16(v); r = v - h (exact); l = RN16(r * 4096). |v - h - l*2^-12| <= 2^-24|v|.
__global__ __launch_bounds__(256) void split_f32(const float* __restrict__ src,
                                                 _Float16* __restrict__ hi,
                                                 _Float16* __restrict__ lo,
                                                 size_t n_valid) {
    const size_t i8 = (size_t)(blockIdx.x * 256u + threadIdx.x) * 8;
    float vv[8];
    if (i8 < n_valid) {
        float4 v0 = *(const float4*)(src + i8);
        float4 v1 = *(const float4*)(src + i8 + 4);
        vv[0] = v0.x; vv[1] = v0.y; vv[2] = v0.z; vv[3] = v0.w;
        vv[4] = v1.x; vv[5] = v1.y; vv[6] = v1.z; vv[7] = v1.w;
    } else {
#pragma unroll
        for (int j = 0; j < 8; ++j) vv[j] = 0.f;
    }
    half8 h8, l8;
#pragma unroll
    for (int j = 0; j < 8; ++j) {
        _Float16 h = (_Float16)vv[j];               // RN
        float r = __fsub_rn(vv[j], (float)h);       // exact
        h8[j] = h;
        l8[j] = (_Float16)(r * 4096.0f);            // exact shift + one RN
    }
    *(half8*)(hi + i8) = h8;
    *(half8*)(lo + i8) = l8;
}

// ---------------- split-fp16 MFMA GEMM ----------------
// Block tile 128x128, BK=32, 4 waves of 64x64 (4x4 frags of 16x16x32).
__global__ __launch_bounds__(256, 2) void gemm_f16x2(const _Float16* __restrict__ A0,
                                                     const _Float16* __restrict__ A1,
                                                     const _Float16* __restrict__ B0,
                                                     const _Float16* __restrict__ B1,
                                                     float* __restrict__ C) {
    __shared__ _Float16 lds[4][128 * 32];  // A0,A1,B0,B1 tiles: 8 KB each = 32 KB

    const int tid  = threadIdx.x;
    const int wave = tid >> 6;
    const int lane = tid & 63;
    const int bm = blockIdx.y * 128;
    const int bn = blockIdx.x * 128;
    const int wm = (wave >> 1) * 64;
    const int wn = (wave & 1) * 64;

    const int srow  = tid >> 2;        // 0..63
    const int skoff = (tid & 3) * 8;   // 0,8,16,24

    f32x4 acc0[4][4], acc1[4][4];
#pragma unroll
    for (int i = 0; i < 4; ++i)
#pragma unroll
        for (int j = 0; j < 4; ++j) {
            acc0[i][j] = (f32x4){0.f, 0.f, 0.f, 0.f};
            acc1[i][j] = (f32x4){0.f, 0.f, 0.f, 0.f};
        }

    const int quad = lane >> 4;
    const int l16  = lane & 15;

    for (int k0 = 0; k0 < NIN_K; k0 += 32) {
        __syncthreads();  // previous compute done before overwriting LDS
#pragma unroll
        for (int c = 0; c < 2; ++c) {
            const size_t ga = (size_t)(bm + c * 64 + srow) * NIN_K + k0 + skoff;
            const size_t gb = (size_t)(bn + c * 64 + srow) * NIN_K + k0 + skoff;
            const int ldst = (c * 64 + wave * 16) * 32;  // wave-uniform base
            GLL16(A0 + ga, &lds[0][ldst]);
            GLL16(A1 + ga, &lds[1][ldst]);
            GLL16(B0 + gb, &lds[2][ldst]);
            GLL16(B1 + gb, &lds[3][ldst]);
        }
        __syncthreads();  // drains vmcnt: staging complete

        // B-frags hoisted (32 regs resident); A-frags loaded per-i (8 regs live)
        half8 b0f[4], b1f[4];
#pragma unroll
        for (int j = 0; j < 4; ++j) {
            const int off = (wn + j * 16 + l16) * 32 + quad * 8;
            b0f[j] = *(const half8*)&lds[2][off];
            b1f[j] = *(const half8*)&lds[3][off];
        }
#pragma unroll
        for (int i = 0; i < 4; ++i) {
            const int off = (wm + i * 16 + l16) * 32 + quad * 8;
            const half8 a0f = *(const half8*)&lds[0][off];
            const half8 a1f = *(const half8*)&lds[1][off];
#pragma unroll
            for (int j = 0; j < 4; ++j) {
                acc0[i][j] = __builtin_amdgcn_mfma_f32_16x16x32_f16(a0f, b0f[j], acc0[i][j], 0, 0, 0);
                acc1[i][j] = __builtin_amdgcn_mfma_f32_16x16x32_f16(a0f, b1f[j], acc1[i][j], 0, 0, 0);
                acc1[i][j] = __builtin_amdgcn_mfma_f32_16x16x32_f16(a1f, b0f[j], acc1[i][j], 0, 0, 0);
            }
        }
    }

    // C/D layout (m89-verified): col = lane&15, row = quad*4 + reg
    const float s = 1.0f / 4096.0f;
#pragma unroll
    for (int i = 0; i < 4; ++i)
#pragma unroll
        for (int j = 0; j < 4; ++j) {
            const int m = bm + wm + i * 16 + quad * 4;
            const int n = bn + wn + j * 16 + l16;
            float* cp = C + (size_t)m * NOUT_N + n;
#pragma unroll
            for (int r = 0; r < 4; ++r)
                cp[(size_t)r * NOUT_N] = __fmaf_rn(acc1[i][j][r], s, acc0[i][j][r]);
        }
}

// ---------------- fallback fp32 GEMM (round-1 proven; reads RAW x/w) ----------------
#define BM 64
#define BN 64
#define BK 16
#define PAD 4
__global__ __launch_bounds__(256) void gemm_bt(const float* __restrict__ A,
                                               const float* __restrict__ B,
                                               float* __restrict__ C,
                                               int M, int N, int K) {
    __shared__ float As[BK][BM + PAD];
    __shared__ float Bs[BK][BN + PAD];
    const int bm = blockIdx.y * BM, bn = blockIdx.x * BN;
    const int tid = threadIdx.x;
    const int tx = tid & 15, ty = tid >> 4;
    const int lrow = tid >> 2, lk = (tid & 3) * 4;
    float acc[4][4];
#pragma unroll
    for (int i = 0; i < 4; ++i)
#pragma unroll
        for (int j = 0; j < 4; ++j) acc[i][j] = 0.0f;
    for (int k0 = 0; k0 < K; k0 += BK) {
        const int am = bm + lrow;
        float4 av = (am < M) ? *(const float4*)(A + (size_t)am * K + k0 + lk)
                             : make_float4(0.f, 0.f, 0.f, 0.f);
        As[lk + 0][lrow] = av.x; As[lk + 1][lrow] = av.y;
        As[lk + 2][lrow] = av.z; As[lk + 3][lrow] = av.w;
        float4 bv = *(const float4*)(B + (size_t)(bn + lrow) * K + k0 + lk);
        Bs[lk + 0][lrow] = bv.x; Bs[lk + 1][lrow] = bv.y;
        Bs[lk + 2][lrow] = bv.z; Bs[lk + 3][lrow] = bv.w;
        __syncthreads();
#pragma unroll
        for (int k = 0; k < BK; ++k) {
            float a[4], b[4];
#pragma unroll
            for (int i = 0; i < 4; ++i) a[i] = As[k][ty * 4 + i];
#pragma unroll
            for (int j = 0; j < 4; ++j) b[j] = Bs[k][tx * 4 + j];
#pragma unroll
            for (int i = 0; i < 4; ++i)
#pragma unroll
                for (int j = 0; j < 4; ++j) acc[i][j] += a[i] * b[j];
        }
        __syncthreads();
    }
#pragma unroll
    for (int i = 0; i < 4; ++i) {
        const int m = bm + ty * 4 + i;
        if (m < M) {
            float* cp = C + (size_t)m * N + bn + tx * 4;
#pragma unroll
            for (int j = 0; j < 4; ++j) cp[j] = acc[i][j];
        }
    }
}

// ---------------- sequential LIF scan, 32-deep register pipeline ----------------
// Loads are UNCONDITIONAL with scalar-clamped index so pf[] stays in VGPRs
// (conditional writes demoted it to scratch in round 4: VGPR_Count=24, 625 us).
#define SCAN_D 32
__global__ __launch_bounds__(64) void lif_scan(const float* __restrict__ inp,
                                               const float* __restrict__ v_th_p,
                                               const float* __restrict__ v_rest_p,
                                               const float* __restrict__ v_reset_p,
                                               const float* __restrict__ t_ref_p,
                                               const float* __restrict__ tau_p,
                                               float* __restrict__ out,
                                               int T, int N) {
    const int j = blockIdx.x * 64 + threadIdx.x;
    if (j >= N) return;
    const float vth = v_th_p[j], vrest = v_rest_p[j], vres = v_reset_p[j];
    const float tref = t_ref_p[j];
    const float c = __fmul_rn(0.001f, tau_p[j]);
    float v = vrest, refrac = 0.0f;
    out[j] = 0.0f;

    float pf[SCAN_D];
#pragma unroll
    for (int d = 0; d < SCAN_D; ++d) pf[d] = inp[(size_t)(1 + d) * N + j];

    int base = 1;
    for (; base + SCAN_D <= T; base += SCAN_D) {
#pragma unroll
        for (int d = 0; d < SCAN_D; ++d) {
            const float in = pf[d];
            int tf = base + d + SCAN_D;            // scalar (base uniform, d const)
            tf = (tf < T) ? tf : (T - 1);          // scalar select, branchless
            pf[d] = inp[(size_t)tf * N + j];       // unconditional load
            const float dd = __fmul_rn(c, __fsub_rn(v, vrest));
            v = __fsub_rn(v, dd);
            v = (refrac == 0.0f) ? __fadd_rn(v, in) : v;
            refrac = (refrac > 0.0f) ? (refrac - 0.001f) : 0.0f;
            const bool s = (__fsub_rn(v, vth) >= 0.0f);
            out[(size_t)(base + d) * N + j] = s ? 1.0f : 0.0f;
            refrac = s ? tref : refrac;
            v = s ? vres : v;
        }
    }
#pragma unroll
    for (int d = 0; d < SCAN_D; ++d) {
        const int t = base + d;
        if (t < T) {
            const float in = pf[d];
            const float dd = __fmul_rn(c, __fsub_rn(v, vrest));
            v = __fsub_rn(v, dd);
            v = (refrac == 0.0f) ? __fadd_rn(v, in) : v;
            refrac = (refrac > 0.0f) ? (refrac - 0.001f) : 0.0f;
            const bool s = (__fsub_rn(v, vth) >= 0.0f);
            out[(size_t)t * N + j] = s ? 1.0f : 0.0f;
            refrac = s ? tref : refrac;
            v = s ? vres : v;
        }
    }
}

extern "C" void kernel_launch(void* const* d_in, const int* in_sizes, int n_in,
                              void* d_out, int out_size, void* d_ws, size_t ws_size,
                              hipStream_t stream) {
    const float* x       = (const float*)d_in[0];
    const float* w       = (const float*)d_in[1];
    const float* v_th    = (const float*)d_in[2];
    const float* v_rest  = (const float*)d_in[3];
    const float* v_reset = (const float*)d_in[4];
    const float* t_ref   = (const float*)d_in[5];
    const float* tau     = (const float*)d_in[6];
    float* out = (float*)d_out;

    const size_t LIF_B = (size_t)MPAD * NOUT_N * 4;        //  32 MiB
    const size_t XS_B  = (size_t)MPAD * NIN_K * 2;         //  32 MiB each
    const size_t WS_B  = (size_t)NOUT_N * NIN_K * 2;       //  64 MiB each
    const size_t NEED  = LIF_B + 2 * XS_B + 2 * WS_B;      // 224 MiB

    char* ws = (char*)d_ws;
    float* lif = (float*)ws;

    if (ws_size >= NEED) {
        _Float16* x0 = (_Float16*)(ws + LIF_B);
        _Float16* x1 = (_Float16*)(ws + LIF_B + XS_B);
        _Float16* w0 = (_Float16*)(ws + LIF_B + 2 * XS_B);
        _Float16* w1 = (_Float16*)(ws + LIF_B + 2 * XS_B + WS_B);

        const size_t nx = (size_t)MPAD * NIN_K;
        split_f32<<<nx / 8 / 256, 256, 0, stream>>>(x, x0, x1,
                                                    (size_t)T_STEPS * NIN_K);
        const size_t nw = (size_t)NOUT_N * NIN_K;
        split_f32<<<nw / 8 / 256, 256, 0, stream>>>(w, w0, w1, nw);

        dim3 g(NOUT_N / 128, MPAD / 128);
        gemm_f16x2<<<g, 256, 0, stream>>>(x0, x1, w0, w1, lif);
    } else {
        dim3 g(NOUT_N / BN, (T_STEPS + BM - 1) / BM);
        gemm_bt<<<g, 256, 0, stream>>>(x, w, lif, T_STEPS, NOUT_N, NIN_K);
    }

    lif_scan<<<NOUT_N / 64, 64, 0, stream>>>(lif, v_th, v_rest, v_reset, t_ref, tau,
                                             out, T_STEPS, NOUT_N);
}

// Round 6
// 721.367 us; speedup vs baseline: 2.0349x; 1.0973x over previous
//
#include <hip/hip_runtime.h>
#include <hip/hip_bf16.h>

// LIF layer: lif_input[T,NOUT] = x[T,NIN] @ W[NOUT,NIN]^T (fp32), then sequential scan.
// fp32 GEMM on matrix pipe via fp16 2-way SCALED split, 3 MFMA products:
//   a = a0 + a1*2^-12 (a1 pre-scaled by 2^12: dodges fp16 subnormal flush)
//   C = acc0(A0B0) + 2^-12 * acc1(A0B1 + A1B0); error ~2^-24|ab| (fp32-noise level).
// Round-6 changes:
//  - BK=64: halves the number of barrier/vmcnt-drain events (the dominant stall
//    at MfmaUtil 41%). LDS 64 KB/block, still 2 blocks/CU (128 <= 160 KB).
//  - in-GEMM bank swizzle: per-lane GLOBAL address picks k-slot (l&7)^(row&7);
//    fragment read XORs back. Breaks the 128B-row-stride full-bank collision.
//  - scan: pipeline with COMPILE-TIME-ONLY pf[] indices (124 groups x 16 + a
//    15-step register-only tail). Round 5's dynamic-index tail likely demoted
//    pf[] to scratch (~250 us inferred). Prefetch rows <= 2015 are valid zeros
//    (x zero-padded to 2048 rows in split).

#define T_STEPS 2000
#define NIN_K   8192
#define NOUT_N  4096
#define MPAD    2048

typedef __attribute__((ext_vector_type(8))) _Float16 half8;  // 8 fp16 = 4 VGPRs
typedef __attribute__((ext_vector_type(4))) float f32x4;

#define GLL16(g, l)                                                              \
    __builtin_amdgcn_global_load_lds(                                            \
        (const __attribute__((address_space(1))) void*)(g),                      \
        (__attribute__((address_space(3))) void*)(l), 16, 0, 0)

// ---------------- decompose: fp32 -> (hi, lo*2^12) fp16 ----------------
__global__ __launch_bounds__(256) void split_f32(const float* __restrict__ src,
                                                 _Float16* __restrict__ hi,
                                                 _Float16* __restrict__ lo,
                                                 size_t n_valid) {
    const size_t i8 = (size_t)(blockIdx.x * 256u + threadIdx.x) * 8;
    float vv[8];
    if (i8 < n_valid) {
        float4 v0 = *(const float4*)(src + i8);
        float4 v1 = *(const float4*)(src + i8 + 4);
        vv[0] = v0.x; vv[1] = v0.y; vv[2] = v0.z; vv[3] = v0.w;
        vv[4] = v1.x; vv[5] = v1.y; vv[6] = v1.z; vv[7] = v1.w;
    } else {
#pragma unroll
        for (int j = 0; j < 8; ++j) vv[j] = 0.f;
    }
    half8 h8, l8;
#pragma unroll
    for (int j = 0; j < 8; ++j) {
        _Float16 h = (_Float16)vv[j];               // RN
        float r = __fsub_rn(vv[j], (float)h);       // exact
        h8[j] = h;
        l8[j] = (_Float16)(r * 4096.0f);            // exact shift + one RN
    }
    *(half8*)(hi + i8) = h8;
    *(half8*)(lo + i8) = l8;
}

// ---------------- split-fp16 MFMA GEMM, BK=64 ----------------
// Block tile 128x128, 4 waves of 64x64 (4x4 frags of 16x16x32), 128 K-iters.
// LDS row layout: [row][64 halves] = 128 B/row; 16B slot s of row r holds TRUE
// k-group s^(r&7) (stage-side per-lane global-address swizzle). Fragment for
// (kstep,quad) reads slot (kstep*4+quad)^(r&7) -> 8 distinct banks, 2-way, free.
__global__ __launch_bounds__(256, 2) void gemm_f16x2(const _Float16* __restrict__ A0,
                                                     const _Float16* __restrict__ A1,
                                                     const _Float16* __restrict__ B0,
                                                     const _Float16* __restrict__ B1,
                                                     float* __restrict__ C) {
    __shared__ _Float16 lds[4][128 * 64];  // A0,A1,B0,B1: 16 KB each = 64 KB

    const int tid  = threadIdx.x;
    const int wave = tid >> 6;
    const int lane = tid & 63;
    const int bm = blockIdx.y * 128;
    const int bn = blockIdx.x * 128;
    const int wm = (wave >> 1) * 64;
    const int wn = (wave & 1) * 64;

    // Staging: per c-chunk, thread covers row c*32 + (tid>>3), 16B slot tid&7.
    // Global k-group swizzled: (tid&7) ^ ((tid>>3)&7)  [(tid>>3)&7 == row&7]
    const int srow = tid >> 3;                       // 0..31
    const int skswz = ((tid & 7) ^ (srow & 7)) * 8;  // halves

    f32x4 acc0[4][4], acc1[4][4];
#pragma unroll
    for (int i = 0; i < 4; ++i)
#pragma unroll
        for (int j = 0; j < 4; ++j) {
            acc0[i][j] = (f32x4){0.f, 0.f, 0.f, 0.f};
            acc1[i][j] = (f32x4){0.f, 0.f, 0.f, 0.f};
        }

    const int quad = lane >> 4;
    const int l16  = lane & 15;

    for (int k0 = 0; k0 < NIN_K; k0 += 64) {
        __syncthreads();  // previous compute done before overwriting LDS
#pragma unroll
        for (int c = 0; c < 4; ++c) {  // 4 chunks of 32 rows
            const size_t ga = (size_t)(bm + c * 32 + srow) * NIN_K + k0 + skswz;
            const size_t gb = (size_t)(bn + c * 32 + srow) * NIN_K + k0 + skswz;
            const int base = (c * 32 + wave * 8) * 64;  // wave-uniform (HW adds lane*16B)
            GLL16(A0 + ga, &lds[0][base]);
            GLL16(A1 + ga, &lds[1][base]);
            GLL16(B0 + gb, &lds[2][base]);
            GLL16(B1 + gb, &lds[3][base]);
        }
        __syncthreads();  // staging complete

#pragma unroll
        for (int ks = 0; ks < 2; ++ks) {  // two K=32 sub-steps
            half8 b0f[4], b1f[4];
#pragma unroll
            for (int j = 0; j < 4; ++j) {
                const int row = wn + j * 16 + l16;
                const int off = row * 64 + ((ks * 4 + quad) ^ (row & 7)) * 8;
                b0f[j] = *(const half8*)&lds[2][off];
                b1f[j] = *(const half8*)&lds[3][off];
            }
#pragma unroll
            for (int i = 0; i < 4; ++i) {
                const int row = wm + i * 16 + l16;
                const int off = row * 64 + ((ks * 4 + quad) ^ (row & 7)) * 8;
                const half8 a0f = *(const half8*)&lds[0][off];
                const half8 a1f = *(const half8*)&lds[1][off];
#pragma unroll
                for (int j = 0; j < 4; ++j) {
                    acc0[i][j] = __builtin_amdgcn_mfma_f32_16x16x32_f16(a0f, b0f[j], acc0[i][j], 0, 0, 0);
                    acc1[i][j] = __builtin_amdgcn_mfma_f32_16x16x32_f16(a0f, b1f[j], acc1[i][j], 0, 0, 0);
                    acc1[i][j] = __builtin_amdgcn_mfma_f32_16x16x32_f16(a1f, b0f[j], acc1[i][j], 0, 0, 0);
                }
            }
        }
    }

    // C/D layout (m89-verified): col = lane&15, row = quad*4 + reg
    const float s = 1.0f / 4096.0f;
#pragma unroll
    for (int i = 0; i < 4; ++i)
#pragma unroll
        for (int j = 0; j < 4; ++j) {
            const int m = bm + wm + i * 16 + quad * 4;
            const int n = bn + wn + j * 16 + l16;
            float* cp = C + (size_t)m * NOUT_N + n;
#pragma unroll
            for (int r = 0; r < 4; ++r)
                cp[(size_t)r * NOUT_N] = __fmaf_rn(acc1[i][j][r], s, acc0[i][j][r]);
        }
}

// ---------------- fallback fp32 GEMM (round-1 proven; reads RAW x/w) ----------------
#define BM 64
#define BN 64
#define BK 16
#define PAD 4
__global__ __launch_bounds__(256) void gemm_bt(const float* __restrict__ A,
                                               const float* __restrict__ B,
                                               float* __restrict__ C,
                                               int M, int N, int K) {
    __shared__ float As[BK][BM + PAD];
    __shared__ float Bs[BK][BN + PAD];
    const int bm = blockIdx.y * BM, bn = blockIdx.x * BN;
    const int tid = threadIdx.x;
    const int tx = tid & 15, ty = tid >> 4;
    const int lrow = tid >> 2, lk = (tid & 3) * 4;
    float acc[4][4];
#pragma unroll
    for (int i = 0; i < 4; ++i)
#pragma unroll
        for (int j = 0; j < 4; ++j) acc[i][j] = 0.0f;
    for (int k0 = 0; k0 < K; k0 += BK) {
        const int am = bm + lrow;
        float4 av = (am < M) ? *(const float4*)(A + (size_t)am * K + k0 + lk)
                             : make_float4(0.f, 0.f, 0.f, 0.f);
        As[lk + 0][lrow] = av.x; As[lk + 1][lrow] = av.y;
        As[lk + 2][lrow] = av.z; As[lk + 3][lrow] = av.w;
        float4 bv = *(const float4*)(B + (size_t)(bn + lrow) * K + k0 + lk);
        Bs[lk + 0][lrow] = bv.x; Bs[lk + 1][lrow] = bv.y;
        Bs[lk + 2][lrow] = bv.z; Bs[lk + 3][lrow] = bv.w;
        __syncthreads();
#pragma unroll
        for (int k = 0; k < BK; ++k) {
            float a[4], b[4];
#pragma unroll
            for (int i = 0; i < 4; ++i) a[i] = As[k][ty * 4 + i];
#pragma unroll
            for (int j = 0; j < 4; ++j) b[j] = Bs[k][tx * 4 + j];
#pragma unroll
            for (int i = 0; i < 4; ++i)
#pragma unroll
                for (int j = 0; j < 4; ++j) acc[i][j] += a[i] * b[j];
        }
        __syncthreads();
    }
#pragma unroll
    for (int i = 0; i < 4; ++i) {
        const int m = bm + ty * 4 + i;
        if (m < M) {
            float* cp = C + (size_t)m * N + bn + tx * 4;
#pragma unroll
            for (int j = 0; j < 4; ++j) cp[j] = acc[i][j];
        }
    }
}

// zero-fill pad rows of lif (fallback path only; main path writes them via GEMM)
__global__ void zero_rows(float* __restrict__ p, size_t n) {
    const size_t i = (size_t)blockIdx.x * 256 + threadIdx.x;
    if (i < n) p[i] = 0.0f;
}

// ---------------- sequential LIF scan ----------------
// Pipeline depth 16; ALL pf[] indices are compile-time constants (steady:
// 124 groups x 16; tail: 15 register-only steps). Prefetch rows t+16 <= 2015
// are valid (zero) because lif has 2048 rows, rows >= 2000 computed from
// zero-padded x.
__global__ __launch_bounds__(64) void lif_scan(const float* __restrict__ inp,
                                               const float* __restrict__ v_th_p,
                                               const float* __restrict__ v_rest_p,
                                               const float* __restrict__ v_reset_p,
                                               const float* __restrict__ t_ref_p,
                                               const float* __restrict__ tau_p,
                                               float* __restrict__ out) {
    const int j = blockIdx.x * 64 + threadIdx.x;
    const int N = NOUT_N;
    const float vth = v_th_p[j], vrest = v_rest_p[j], vres = v_reset_p[j];
    const float tref = t_ref_p[j];
    const float c = __fmul_rn(0.001f, tau_p[j]);
    float v = vrest, refrac = 0.0f;
    out[j] = 0.0f;  // row 0 stays zero

    float pf[16];
#pragma unroll
    for (int d = 0; d < 16; ++d) pf[d] = inp[(size_t)(1 + d) * N + j];

    // steady: t = 1 .. 1984  (124 groups of 16)
    for (int g = 0; g < 124; ++g) {
        const int tbase = 1 + g * 16;
#pragma unroll
        for (int d = 0; d < 16; ++d) {
            const int t = tbase + d;
            const float in = pf[d];
            pf[d] = inp[(size_t)(t + 16) * N + j];  // unconditional, row <= 2015
            const float dd = __fmul_rn(c, __fsub_rn(v, vrest));
            v = __fsub_rn(v, dd);
            v = (refrac == 0.0f) ? __fadd_rn(v, in) : v;
            refrac = (refrac > 0.0f) ? (refrac - 0.001f) : 0.0f;
            const bool s = (__fsub_rn(v, vth) >= 0.0f);
            out[(size_t)t * N + j] = s ? 1.0f : 0.0f;
            refrac = s ? tref : refrac;
            v = s ? vres : v;
        }
    }
    // tail: t = 1985 .. 1999 (15 steps), pf[e] holds row 1985+e; no loads
#pragma unroll
    for (int e = 0; e < 15; ++e) {
        const int t = 1985 + e;
        const float in = pf[e];
        const float dd = __fmul_rn(c, __fsub_rn(v, vrest));
        v = __fsub_rn(v, dd);
        v = (refrac == 0.0f) ? __fadd_rn(v, in) : v;
        refrac = (refrac > 0.0f) ? (refrac - 0.001f) : 0.0f;
        const bool s = (__fsub_rn(v, vth) >= 0.0f);
        out[(size_t)t * N + j] = s ? 1.0f : 0.0f;
        refrac = s ? tref : refrac;
        v = s ? vres : v;
    }
}

extern "C" void kernel_launch(void* const* d_in, const int* in_sizes, int n_in,
                              void* d_out, int out_size, void* d_ws, size_t ws_size,
                              hipStream_t stream) {
    const float* x       = (const float*)d_in[0];
    const float* w       = (const float*)d_in[1];
    const float* v_th    = (const float*)d_in[2];
    const float* v_rest  = (const float*)d_in[3];
    const float* v_reset = (const float*)d_in[4];
    const float* t_ref   = (const float*)d_in[5];
    const float* tau     = (const float*)d_in[6];
    float* out = (float*)d_out;

    const size_t LIF_B = (size_t)MPAD * NOUT_N * 4;        //  32 MiB
    const size_t XS_B  = (size_t)MPAD * NIN_K * 2;         //  32 MiB each
    const size_t WS_B  = (size_t)NOUT_N * NIN_K * 2;       //  64 MiB each
    const size_t NEED  = LIF_B + 2 * XS_B + 2 * WS_B;      // 224 MiB

    char* ws = (char*)d_ws;
    float* lif = (float*)ws;

    if (ws_size >= NEED) {
        _Float16* x0 = (_Float16*)(ws + LIF_B);
        _Float16* x1 = (_Float16*)(ws + LIF_B + XS_B);
        _Float16* w0 = (_Float16*)(ws + LIF_B + 2 * XS_B);
        _Float16* w1 = (_Float16*)(ws + LIF_B + 2 * XS_B + WS_B);

        const size_t nx = (size_t)MPAD * NIN_K;
        split_f32<<<nx / 8 / 256, 256, 0, stream>>>(x, x0, x1,
                                                    (size_t)T_STEPS * NIN_K);
        const size_t nw = (size_t)NOUT_N * NIN_K;
        split_f32<<<nw / 8 / 256, 256, 0, stream>>>(w, w0, w1, nw);

        dim3 g(NOUT_N / 128, MPAD / 128);
        gemm_f16x2<<<g, 256, 0, stream>>>(x0, x1, w0, w1, lif);
    } else {
        dim3 g(NOUT_N / BN, (T_STEPS + BM - 1) / BM);
        gemm_bt<<<g, 256, 0, stream>>>(x, w, lif, T_STEPS, NOUT_N, NIN_K);
        const size_t padn = (size_t)(MPAD - T_STEPS) * NOUT_N;
        zero_rows<<<(padn + 255) / 256, 256, 0, stream>>>(lif + (size_t)T_STEPS * NOUT_N, padn);
    }

    lif_scan<<<NOUT_N / 64, 64, 0, stream>>>(lif, v_th, v_rest, v_reset, t_ref, tau, out);
}